// Round 1
// baseline (374.060 us; speedup 1.0000x reference)
//
#include <hip/hip_runtime.h>
#include <hip/hip_fp16.h>

// Problem: Topo_60653528154131
//   x:[256,3,256,25] f32, centres:[64,2] f32, sharpness:[64,2] f32 -> out:[64] f32
//
// SINGLE fused persistent kernel (grid 256 x 1024). The old 4-kernel pipeline's
// inter-node gaps (~3 x 10-20 us) were the dominant cost (work sums to ~30 us vs
// 93 us measured). 256 blocks @ ~90 KB LDS = 1 block/CU on 256 CUs -> all blocks
// co-resident -> device-scope flag spin-barriers are deadlock-free and ~2-3 us.
//
// Phases (same proven math as the 4-kernel version):
//   P1: m[n,v] = mean_{c,t} x (block b owns row b) + Mp INF-init        [barrier1]
//   P2: feat (redundant per block), D2 row b -> d16row (LDS, no global
//       D16 round-trip any more), row-min key -> rowKeyG, block0 min/max [barrier2]
//   P3: deterministic Boruvka round-1 replay from rowKeyG (identical cmap in every
//       block), fold own row into global Mp via atomicMin; block 0 keeps deaths
//       in persistent LDS                                               [barrier3, block0-only wait]
//   P4: block 0 alone: rounds 2+ on Mp in LDS, structure-element layer.
//
// Cross-iteration safety of the flag barriers: ws (256 MiB) is poison-filled by
// the harness every iteration (the 262144 KB fillBuffer dispatches), so stale
// MAGIC values cannot survive; magics use 4 distinct bytes so no byte-pattern
// fill can fake them. Bounded spin (~1 s) converts any bug into a clean fail
// instead of a hang.
//
// ws layout:
//   m       [6400]  f32 @ 0
//   rowKeyG [256]   u32 @ 28672
//   flags   [3*256] u32 @ 32768
//   Mp      [128*132] u32 @ 196608

#define WS_M    0
#define WS_RK   28672
#define WS_FLG  32768
#define WS_MP   196608

#define INF32 0xFFFFFFFFu
#define MPSTR 132
#define SA 132   // u32 stride, buffer A (cap 128 rows)
#define SB 68    // u32 stride, buffer B (cap 64 rows)
#define OFF_B (128 * SA)

#define MAGIC1 0x1B9E4C7Du
#define MAGIC2 0x2C8F5D6Eu
#define MAGIC3 0x3DA06E5Fu

// wave64 min-reduce step via DPP: invalid lanes keep old=INF
template <int CTRL>
__device__ __forceinline__ unsigned int dpp_min_step(unsigned int v) {
    unsigned int t = (unsigned int)__builtin_amdgcn_update_dpp(
        (int)0xFFFFFFFF, (int)v, CTRL, 0xF, 0xF, false);
    return (t < v) ? t : v;
}

// ---------------- wave0 Boruvka phase (DETERMINISTIC) ----------------
// hook -> 2-cycle break (optional death record) -> async pointer jump ->
// ballot-rank renumber (deterministic: identical cmap/nc in every block).
template <bool RECORD>
__device__ __forceinline__ void wave0_phase(int n, int lane,
        unsigned int* rowKeyS, unsigned char* parentS, unsigned char* newidS,
        unsigned char* cmapS, float* deaths, unsigned int* ncS, unsigned int* dcS) {
    unsigned int par[4];
    #pragma unroll
    for (int s = 0; s < 4; ++s) {         // hook
        const int i = lane + 64 * s;
        if (i < n) {
            const unsigned int rk = rowKeyS[i];
            const unsigned int u = (rk >> 8) & 0xFFu, v = rk & 0xFFu;
            unsigned int p = (u == (unsigned int)i) ? v : u;
            if (rk == INF32) p = (unsigned int)i;
            par[s] = p;
            parentS[i] = (unsigned char)p;
        }
    }
    #pragma unroll
    for (int s = 0; s < 4; ++s) {         // break mutual 2-cycles
        const int i = lane + 64 * s;
        if (i < n) {
            const unsigned int p = par[s];
            if (p != (unsigned int)i) {
                if (parentS[p] == (unsigned char)i && (unsigned int)i < p) {
                    parentS[i] = (unsigned char)i;   // winner stays root
                } else if (RECORD) {
                    const unsigned int d = atomicAdd(dcS, 1u);
                    const unsigned int rk = rowKeyS[i];
                    deaths[d] = sqrtf(__half2float(__ushort_as_half(
                        (unsigned short)(rk >> 16))));
                }
            }
        }
    }
    for (;;) {                            // async pointer jump
        bool ch = false;
        #pragma unroll
        for (int s = 0; s < 4; ++s) {
            const int i = lane + 64 * s;
            if (i < n) {
                const unsigned char p0 = parentS[i];
                const unsigned char np = parentS[p0];
                if (np != p0) { ch = true; parentS[i] = np; }
            }
        }
        if (__ballot(ch) == 0ull) break;
    }
    bool isr[4];
    #pragma unroll
    for (int s = 0; s < 4; ++s) {
        const int i = lane + 64 * s;
        isr[s] = (i < n) && (parentS[i] == (unsigned char)i);
    }
    unsigned int base = 0;
    const unsigned long long below = (1ull << lane) - 1ull;
    #pragma unroll
    for (int s = 0; s < 4; ++s) {
        const unsigned long long mask = __ballot(isr[s]);   // uniform execution
        if (isr[s]) {
            const int i = lane + 64 * s;
            newidS[i] = (unsigned char)(base + __popcll(mask & below));
        }
        base += (unsigned int)__popcll(mask);
    }
    if (lane == 0) *ncS = base;
    #pragma unroll
    for (int s = 0; s < 4; ++s) {
        const int i = lane + 64 * s;
        if (i < n) cmapS[i] = newidS[parentS[i]];
    }
}

// ---------------- device-scope flag barrier (all 256 blocks co-resident) -----
__device__ __forceinline__ void grid_barrier(unsigned int* flagBase, int b,
                                             int tid, unsigned int magic) {
    __syncthreads();                 // block's prior work done
    __threadfence();                 // release: L1 drain + L2 wb to coherent point
    if (tid == 0) atomicExch(&flagBase[b], magic);
    if (tid < 256) {
        unsigned int guard = 0;
        while (__hip_atomic_load(&flagBase[tid], __ATOMIC_RELAXED,
                                 __HIP_MEMORY_SCOPE_AGENT) != magic) {
            __builtin_amdgcn_s_sleep(1);
            if (++guard > (1u << 22)) break;   // ~1 s: fail clean, never hang
        }
    }
    __threadfence();                 // acquire: invalidate L1/remote-L2 lines
    __syncthreads();
}

// ---------------- the fused kernel ----------------
__global__ void __launch_bounds__(1024) k_fused(
        const float* __restrict__ x, const float* __restrict__ centres,
        const float* __restrict__ sharp, float* __restrict__ out,
        float* __restrict__ m, unsigned int* __restrict__ rowKeyG,
        unsigned int* __restrict__ Mp, unsigned int* __restrict__ flags) {
    // phase-overlaid LDS (max member 89 KB) + small persistent state
    __shared__ __align__(16) union {
        struct { float sums[25]; } p1;
        struct { float mS[6400]; float featS[6400]; } p2;                 // 51.2 KB
        struct { unsigned int Mb[128 * SA + 64 * SB]; float outpart[1024]; } p4; // 89 KB
    } U;
    __shared__ unsigned int rowKeyS[256];
    __shared__ unsigned char parentS[256], newidS[256], cmapS[256];
    __shared__ unsigned int ncS, dcS;
    __shared__ float deaths[256];          // persistent: P3 round-1 + P4 rounds
    __shared__ unsigned int mmS[2];        // persistent: feat min/max (block 0)
    __shared__ unsigned int wred[4];
    __shared__ unsigned short d16row[256]; // persistent: own D2 row, P2 -> P3

    const int b = blockIdx.x;
    const int tid = threadIdx.x;

    // ================= P1: channel+time mean + Mp INF-init =================
    if (tid < 66) Mp[b * 66 + tid] = INF32;   // 256*66 = 16896 = 128*132 exactly
    if (tid < 25) U.p1.sums[tid] = 0.0f;
    __syncthreads();
    if (tid < 200) {
        const float* base = x + (long)b * 19200 + 4 * tid;
        float a0 = 0.f, a1 = 0.f, a2 = 0.f, a3 = 0.f;
        #pragma unroll
        for (int i = 0; i < 24; ++i) {
            float4 v = *reinterpret_cast<const float4*>(base + 800 * i);
            a0 += v.x; a1 += v.y; a2 += v.z; a3 += v.w;
        }
        const int v0 = (4 * tid) % 25;
        atomicAdd(&U.p1.sums[v0], a0);
        atomicAdd(&U.p1.sums[(v0 + 1) % 25], a1);
        atomicAdd(&U.p1.sums[(v0 + 2) % 25], a2);
        atomicAdd(&U.p1.sums[(v0 + 3) % 25], a3);
    }
    __syncthreads();
    if (tid < 25) m[b * 25 + tid] = U.p1.sums[tid] * (1.0f / 768.0f);

    grid_barrier(flags, b, tid, MAGIC1);

    // ================= P2: feat + D2 row + row-min key + minmax ============
    if (tid == 0) { mmS[0] = 0x7F800000u; mmS[1] = 0u; }
    for (int o = tid; o < 1600; o += 1024)
        reinterpret_cast<float4*>(U.p2.mS)[o] =
            reinterpret_cast<const float4*>(m)[o];
    __syncthreads();
    if (tid < 256) {
        float r[25];
        #pragma unroll
        for (int v = 0; v < 25; ++v) r[v] = U.p2.mS[tid * 25 + v];
        float S1 = 0.f, S2 = 0.f;
        #pragma unroll
        for (int v = 0; v < 25; ++v) { S1 += r[v]; S2 += r[v] * r[v]; }
        float fmn = 1e30f, fmx = -1e30f;
        #pragma unroll
        for (int w = 0; w < 25; ++w) {
            float q = S2 - 2.f * r[w] * S1 + 25.f * r[w] * r[w];
            q = fmaxf(q, 0.f);
            float f = sqrtf(q);
            U.p2.featS[tid * 25 + w] = f;
            fmn = fminf(fmn, f); fmx = fmaxf(fmx, f);
        }
        if (b == 0) {
            atomicMin(&mmS[0], __float_as_uint(fmn));
            atomicMax(&mmS[1], __float_as_uint(fmx));
        }
    }
    __syncthreads();
    if (tid < 256) {
        float fi[25];
        #pragma unroll
        for (int v = 0; v < 25; ++v) fi[v] = U.p2.featS[b * 25 + v];
        float s = 0.f;
        #pragma unroll
        for (int v = 0; v < 25; ++v) {
            float d = fi[v] - U.p2.featS[tid * 25 + v]; s += d * d;
        }
        const unsigned int w16 = (unsigned int)__half_as_ushort(__float2half(s));
        d16row[tid] = (unsigned short)w16;          // stays in LDS for P3
        const unsigned int lo = (tid < b) ? tid : b, hi = (tid < b) ? b : tid;
        unsigned int key = (tid == b) ? INF32 : ((w16 << 16) | (lo << 8) | hi);
        key = dpp_min_step<0x111>(key);
        key = dpp_min_step<0x112>(key);
        key = dpp_min_step<0x114>(key);
        key = dpp_min_step<0x118>(key);
        key = dpp_min_step<0x142>(key);
        key = dpp_min_step<0x143>(key);
        if ((tid & 63) == 63) wred[tid >> 6] = key;
    }
    __syncthreads();
    if (tid == 0) {
        unsigned int b0 = wred[0] < wred[1] ? wred[0] : wred[1];
        unsigned int b1 = wred[2] < wred[3] ? wred[2] : wred[3];
        rowKeyG[b] = b0 < b1 ? b0 : b1;
    }

    grid_barrier(flags + 256, b, tid, MAGIC2);

    // ================= P3: round-1 replay + distributed fold ===============
    if (tid < 256) rowKeyS[tid] = rowKeyG[tid];
    if (tid == 0) dcS = 0;
    __syncthreads();
    if (tid < 64) {
        if (b == 0)
            wave0_phase<true>(256, tid, rowKeyS, parentS, newidS, cmapS,
                              deaths, &ncS, &dcS);   // deaths persist in LDS
        else
            wave0_phase<false>(256, tid, rowKeyS, parentS, newidS, cmapS,
                               nullptr, &ncS, nullptr);
    }
    __syncthreads();
    if (tid < 256) {
        const unsigned int ca = cmapS[b];
        const unsigned int cb = cmapS[tid];
        if (ca != cb) {
            const unsigned int w16 = (unsigned int)d16row[tid];
            const unsigned int lo = ca < cb ? ca : cb;
            const unsigned int hi = ca < cb ? cb : ca;
            atomicMin(&Mp[ca * MPSTR + cb], (w16 << 16) | (lo << 8) | hi);
        }
    }

    // barrier 3: everyone arrives; only block 0 waits and continues
    __syncthreads();
    __threadfence();
    if (tid == 0) atomicExch(&flags[512 + b], MAGIC3);
    if (b != 0) return;
    if (tid < 256) {
        unsigned int guard = 0;
        while (__hip_atomic_load(&flags[512 + tid], __ATOMIC_RELAXED,
                                 __HIP_MEMORY_SCOPE_AGENT) != MAGIC3) {
            __builtin_amdgcn_s_sleep(1);
            if (++guard > (1u << 22)) break;
        }
    }
    __threadfence();
    __syncthreads();

    // ================= P4: Boruvka rounds 2+ + structure layer (block 0) ===
    int n = (int)ncS;
    for (int idx = tid; idx < n * 33; idx += 1024)        // SA=132 -> 33 uint4/row
        reinterpret_cast<uint4*>(U.p4.Mb)[idx] =
            reinterpret_cast<const uint4*>(Mp)[idx];
    __syncthreads();

    int srcOff = 0, srcStr = SA, dstOff = OFF_B, dstStr = SB;
    for (int round = 0; round < 12 && n > 1; ++round) {
        if (tid < n) rowKeyS[tid] = INF32;
        __syncthreads();
        if (tid < 8 * n) {                 // scan: 8 threads per row
            const int a = tid >> 3, sub = tid & 7;
            const unsigned int* row = &U.p4.Mb[srcOff + a * srcStr];
            unsigned int best = INF32;
            for (int b2 = sub; b2 < n; b2 += 8) {
                const unsigned int v = row[b2];
                best = v < best ? v : best;
            }
            if (best != INF32) atomicMin(&rowKeyS[a], best);
        }
        __syncthreads();
        if (tid < 64)
            wave0_phase<true>(n, tid, rowKeyS, parentS, newidS, cmapS,
                              deaths, &ncS, &dcS);
        __syncthreads();
        const int nc = (int)ncS;
        if (nc > 1) {                      // contract src -> dst
            for (int w = tid; w < nc * dstStr; w += 1024)
                U.p4.Mb[dstOff + w] = INF32;
            __syncthreads();
            if (tid < 8 * n) {
                const int a = tid >> 3, sub = tid & 7;
                const unsigned int ca = cmapS[a];
                const unsigned int* row = &U.p4.Mb[srcOff + a * srcStr];
                for (int b2 = sub; b2 < n; b2 += 8) {
                    const unsigned int cb = cmapS[b2];
                    const unsigned int v = row[b2];
                    if (ca != cb && v != INF32) {
                        const unsigned int lo = ca < cb ? ca : cb;
                        const unsigned int hi = ca < cb ? cb : ca;
                        atomicMin(&U.p4.Mb[dstOff + ca * dstStr + cb],
                                  (v & 0xFFFF0000u) | (lo << 8) | hi);
                    }
                }
            }
            __syncthreads();
        }
        const int t1 = srcOff; srcOff = dstOff; dstOff = t1;
        const int t2 = srcStr; srcStr = dstStr; dstStr = t2;
        n = nc;
    }

    // structure-element layer: out[k] = sum_i exp(-c0^2 s0^2 - (d_i-c1)^2 s1^2)
    const float mn = __uint_as_float(mmS[0]);
    const float mx = __uint_as_float(mmS[1]);
    const float inv = 1.0f / (mx - mn);
    const int k = tid & 63;
    const int part = tid >> 6;
    const float c0 = centres[2 * k], c1 = centres[2 * k + 1];
    const float s0 = sharp[2 * k],   s1 = sharp[2 * k + 1];
    const float t0 = c0 * c0 * s0 * s0;
    const float s1sq = s1 * s1;
    float acc = 0.f;
    for (int idx = part; idx < 255; idx += 16) {
        const float d = deaths[idx] * inv - c1;
        acc += __expf(-(t0 + d * d * s1sq));
    }
    U.p4.outpart[tid] = acc;
    __syncthreads();
    if (tid < 64) {
        float s = 0.f;
        #pragma unroll
        for (int pp = 0; pp < 16; ++pp) s += U.p4.outpart[tid + 64 * pp];
        out[tid] = s;
    }
}

extern "C" void kernel_launch(void* const* d_in, const int* in_sizes, int n_in,
                              void* d_out, int out_size, void* d_ws, size_t ws_size,
                              hipStream_t stream) {
    const float* x       = (const float*)d_in[0];
    const float* centres = (const float*)d_in[1];
    const float* sharp   = (const float*)d_in[2];
    float* out = (float*)d_out;
    char* ws = (char*)d_ws;
    float*        m     = (float*)(ws + WS_M);
    unsigned int* rk    = (unsigned int*)(ws + WS_RK);
    unsigned int* flags = (unsigned int*)(ws + WS_FLG);
    unsigned int* Mp    = (unsigned int*)(ws + WS_MP);

    k_fused<<<256, 1024, 0, stream>>>(x, centres, sharp, out, m, rk, Mp, flags);
}

// Round 2
// 197.888 us; speedup vs baseline: 1.8903x; 1.8903x over previous
//
#include <hip/hip_runtime.h>
#include <hip/hip_fp16.h>

// Problem: Topo_60653528154131
//   x:[256,3,256,25] f32, centres:[64,2] f32, sharpness:[64,2] f32 -> out:[64] f32
//
// 2-kernel pipeline (1 inter-kernel gap instead of round-0's 3; round-1 showed
// in-kernel grid barriers cost ~95us each on this part -> kernel boundary is the
// cheapest coherent grid barrier at ~20us).
//
//   K1 k_feat : block n: m-row n = mean_{c,t} x[n]  ->  feat row n (25 vals, via
//               the S1/S2 expansion, bit-identical arithmetic to the verified
//               lineage) -> featG (stride 26 for LDS bank friendliness) + per-row
//               min/max to fmnG/fmxG.
//   K2 k_topo : ONE block, 1024 threads.
//               waves 1..15: produce D16 rows (half bits of D^2, same __float2half
//                 pipeline as verified) into LDS, per-row volatile ready flag
//                 (intra-CU LDS ordering via __threadfence_block -> cheap).
//               wave 0: Prim's MST concurrently, spinning per-row on the ready
//                 flag. MST edge-weight MULTISET is identical for all MSTs, so
//                 Prim == Boruvka deaths multiset; output sums over deaths.
//               then: structure-element layer (same 16-partial form as verified).
//
// ws layout:
//   featG [6656] f32 @ 0      (rows stride 26, col 25 unused)
//   fmnG  [256]  f32 @ 26624
//   fmxG  [256]  f32 @ 27648

#define WS_FEAT 0
#define WS_FMN  26624
#define WS_FMX  27648

#define INF32 0xFFFFFFFFu

// ---------------- K1: mean + feat row + row min/max ----------------
__global__ void __launch_bounds__(256) k_feat(const float* __restrict__ x,
                                              float* __restrict__ featG,
                                              float* __restrict__ fmnG,
                                              float* __restrict__ fmxG) {
    __shared__ float sums[25];
    __shared__ float mrow[25];
    __shared__ float S12[2];
    __shared__ unsigned int bmn, bmx;
    const int n = blockIdx.x;
    const int tid = threadIdx.x;
    if (tid < 25) sums[tid] = 0.0f;
    if (tid == 0) { bmn = 0x7F800000u; bmx = 0u; }
    __syncthreads();
    if (tid < 200) {
        const float* base = x + (long)n * 19200 + 4 * tid;
        float a0 = 0.f, a1 = 0.f, a2 = 0.f, a3 = 0.f;
        #pragma unroll
        for (int i = 0; i < 24; ++i) {
            float4 v = *reinterpret_cast<const float4*>(base + 800 * i);
            a0 += v.x; a1 += v.y; a2 += v.z; a3 += v.w;
        }
        const int v0 = (4 * tid) % 25;
        atomicAdd(&sums[v0], a0);
        atomicAdd(&sums[(v0 + 1) % 25], a1);
        atomicAdd(&sums[(v0 + 2) % 25], a2);
        atomicAdd(&sums[(v0 + 3) % 25], a3);
    }
    __syncthreads();
    if (tid < 25) mrow[tid] = sums[tid] * (1.0f / 768.0f);
    __syncthreads();
    if (tid == 0) {
        float S1 = 0.f, S2 = 0.f;
        #pragma unroll
        for (int v = 0; v < 25; ++v) { S1 += mrow[v]; S2 += mrow[v] * mrow[v]; }
        S12[0] = S1; S12[1] = S2;
    }
    __syncthreads();
    if (tid < 25) {
        const float r = mrow[tid];
        float q = S12[1] - 2.f * r * S12[0] + 25.f * r * r;
        q = fmaxf(q, 0.f);
        const float f = sqrtf(q);
        featG[n * 26 + tid] = f;
        atomicMin(&bmn, __float_as_uint(f));
        atomicMax(&bmx, __float_as_uint(f));
    }
    __syncthreads();
    if (tid == 0) { fmnG[n] = __uint_as_float(bmn); fmxG[n] = __uint_as_float(bmx); }
}

// wave64 min-reduce step via DPP: invalid lanes keep old=INF; result in lane 63
template <int CTRL>
__device__ __forceinline__ unsigned int dpp_min_step(unsigned int v) {
    unsigned int t = (unsigned int)__builtin_amdgcn_update_dpp(
        (int)0xFFFFFFFF, (int)v, CTRL, 0xF, 0xF, false);
    return (t < v) ? t : v;
}

// ---------------- K2: D16 producers + overlapped Prim + structure ----------------
__global__ void __launch_bounds__(1024) k_topo(const float* __restrict__ featG,
                                               const float* __restrict__ fmnG,
                                               const float* __restrict__ fmxG,
                                               const float* __restrict__ centres,
                                               const float* __restrict__ sharp,
                                               float* __restrict__ out) {
    __shared__ __align__(16) union { float featS[6656]; float outpart[1024]; } FS;
    __shared__ unsigned short D16h[65536];      // 128 KB: half bits of D^2
    __shared__ unsigned int rowReady[256];
    __shared__ float deathsS[256];
    __shared__ unsigned int mmS[2];
    const int tid = threadIdx.x;

    if (tid == 0) { mmS[0] = 0x7F800000u; mmS[1] = 0u; }
    if (tid < 256) rowReady[tid] = 0u;
    __syncthreads();
    for (int o = tid; o < 1664; o += 1024)
        reinterpret_cast<float4*>(FS.featS)[o] =
            reinterpret_cast<const float4*>(featG)[o];
    if (tid < 256) {
        atomicMin(&mmS[0], __float_as_uint(fmnG[tid]));
        atomicMax(&mmS[1], __float_as_uint(fmxG[tid]));
    }
    __syncthreads();

    const int wv = tid >> 6, lane = tid & 63;
    volatile unsigned int* rr = rowReady;

    if (wv == 0) {
        // ---------------- Prim's MST (wave 0, 255 iterations) ----------------
        // dist key per lane/slot: (halfbits(D2) << 16) | node_index; u16 half bits
        // of non-negative values compare monotonically as unsigned.
        { unsigned g = 0;
          while (rr[0] == 0u) { __builtin_amdgcn_s_sleep(2); if (++g > (1u<<20)) break; } }
        __threadfence_block();
        unsigned int d0, d1, d2_, d3;
        {
            const unsigned int h0 = D16h[lane];
            const unsigned int h1 = D16h[64 + lane];
            const unsigned int h2 = D16h[128 + lane];
            const unsigned int h3 = D16h[192 + lane];
            d0 = (h0 << 16) | (unsigned)lane;
            d1 = (h1 << 16) | (unsigned)(64 + lane);
            d2_ = (h2 << 16) | (unsigned)(128 + lane);
            d3 = (h3 << 16) | (unsigned)(192 + lane);
        }
        unsigned int tb = 0;                       // in-tree bits for my 4 slots
        if (lane == 0) { tb = 1u; d0 = INF32; }    // node 0 starts in tree
        for (int it = 0; it < 255; ++it) {
            unsigned int a = d0 < d1 ? d0 : d1;
            unsigned int b = d2_ < d3 ? d2_ : d3;
            unsigned int key = a < b ? a : b;
            key = dpp_min_step<0x111>(key);
            key = dpp_min_step<0x112>(key);
            key = dpp_min_step<0x114>(key);
            key = dpp_min_step<0x118>(key);
            key = dpp_min_step<0x142>(key);
            key = dpp_min_step<0x143>(key);
            const unsigned int best = (unsigned int)__builtin_amdgcn_readlane((int)key, 63);
            const unsigned int j = best & 0xFFu;
            if (lane == 0)
                deathsS[it] = sqrtf(__half2float(__ushort_as_half(
                    (unsigned short)(best >> 16))));
            // mark j in-tree BEFORE folding row j (row j contains D[j][j]=0)
            const unsigned int lj = j & 63u;
            const unsigned int slot = j >> 6;
            if ((unsigned)lane == lj) {
                tb |= (1u << slot);
                if (slot == 0u) d0 = INF32;
                else if (slot == 1u) d1 = INF32;
                else if (slot == 2u) d2_ = INF32;
                else d3 = INF32;
            }
            { unsigned g = 0;
              while (rr[j] == 0u) { __builtin_amdgcn_s_sleep(2); if (++g > (1u<<20)) break; } }
            __threadfence_block();
            const unsigned int rb = j << 8;
            const unsigned int h0 = D16h[rb + lane];
            const unsigned int h1 = D16h[rb + 64 + lane];
            const unsigned int h2 = D16h[rb + 128 + lane];
            const unsigned int h3 = D16h[rb + 192 + lane];
            const unsigned int n0 = (h0 << 16) | (unsigned)lane;
            const unsigned int n1 = (h1 << 16) | (unsigned)(64 + lane);
            const unsigned int n2 = (h2 << 16) | (unsigned)(128 + lane);
            const unsigned int n3 = (h3 << 16) | (unsigned)(192 + lane);
            d0 = (tb & 1u) ? INF32 : (n0 < d0 ? n0 : d0);
            d1 = (tb & 2u) ? INF32 : (n1 < d1 ? n1 : d1);
            d2_ = (tb & 4u) ? INF32 : (n2 < d2_ ? n2 : d2_);
            d3 = (tb & 8u) ? INF32 : (n3 < d3 ? n3 : d3);
        }
    } else {
        // ---------------- D16 producers (waves 1..15) ----------------
        for (int r = wv - 1; r < 256; r += 15) {
            float fi[25];
            #pragma unroll
            for (int v = 0; v < 25; ++v) fi[v] = FS.featS[r * 26 + v];  // broadcast
            float s0 = 0.f, s1 = 0.f, s2 = 0.f, s3 = 0.f;
            const int j0 = lane, j1 = 64 + lane, j2 = 128 + lane, j3 = 192 + lane;
            #pragma unroll
            for (int v = 0; v < 25; ++v) {
                const float fv = fi[v];
                const float e0 = fv - FS.featS[j0 * 26 + v]; s0 += e0 * e0;
                const float e1 = fv - FS.featS[j1 * 26 + v]; s1 += e1 * e1;
                const float e2 = fv - FS.featS[j2 * 26 + v]; s2 += e2 * e2;
                const float e3 = fv - FS.featS[j3 * 26 + v]; s3 += e3 * e3;
            }
            const unsigned int rb = (unsigned)r << 8;
            D16h[rb + j0] = __half_as_ushort(__float2half(s0));
            D16h[rb + j1] = __half_as_ushort(__float2half(s1));
            D16h[rb + j2] = __half_as_ushort(__float2half(s2));
            D16h[rb + j3] = __half_as_ushort(__float2half(s3));
            __threadfence_block();                  // LDS writes committed
            if (lane == 0) rr[r] = 1u;              // publish row
        }
    }
    __syncthreads();

    // ---------------- structure-element layer ----------------
    const float mn = __uint_as_float(mmS[0]);
    const float mx = __uint_as_float(mmS[1]);
    const float inv = 1.0f / (mx - mn);
    const int k = tid & 63;
    const int part = tid >> 6;
    const float c0 = centres[2 * k], c1 = centres[2 * k + 1];
    const float sh0 = sharp[2 * k],  sh1 = sharp[2 * k + 1];
    const float t0 = c0 * c0 * sh0 * sh0;
    const float s1sq = sh1 * sh1;
    float acc = 0.f;
    for (int idx = part; idx < 255; idx += 16) {
        const float d = deathsS[idx] * inv - c1;
        acc += __expf(-(t0 + d * d * s1sq));
    }
    FS.outpart[tid] = acc;
    __syncthreads();
    if (tid < 64) {
        float s = 0.f;
        #pragma unroll
        for (int pp = 0; pp < 16; ++pp) s += FS.outpart[tid + 64 * pp];
        out[tid] = s;
    }
}

extern "C" void kernel_launch(void* const* d_in, const int* in_sizes, int n_in,
                              void* d_out, int out_size, void* d_ws, size_t ws_size,
                              hipStream_t stream) {
    const float* x       = (const float*)d_in[0];
    const float* centres = (const float*)d_in[1];
    const float* sharp   = (const float*)d_in[2];
    float* out = (float*)d_out;
    char* ws = (char*)d_ws;
    float* featG = (float*)(ws + WS_FEAT);
    float* fmnG  = (float*)(ws + WS_FMN);
    float* fmxG  = (float*)(ws + WS_FMX);

    k_feat<<<256, 256, 0, stream>>>(x, featG, fmnG, fmxG);
    k_topo<<<1, 1024, 0, stream>>>(featG, fmnG, fmxG, centres, sharp, out);
}

// Round 3
// 112.461 us; speedup vs baseline: 3.3261x; 1.7596x over previous
//
#include <hip/hip_runtime.h>
#include <hip/hip_fp16.h>

// Problem: Topo_60653528154131
//   x:[256,3,256,25] f32, centres:[64,2] f32, sharpness:[64,2] f32 -> out:[64] f32
//
// Cost model (fitted R0/R1/R2): dur_us = C + sum(kernel times), C ~= 57-65 us
// fixed (256MiB ws poison-fill ~43us is inside the timed stream + launch
// overhead). Inter-kernel gaps are ~free. So: minimize total kernel time.
//
// 3-kernel pipeline (all algorithm steps bit-identical to the verified round-0
// lineage; only the work distribution changed):
//   K1 k_feat : block n: mean_{c,t} x[n] -> feat row n (S1/S2 expansion) ->
//               featG (stride 26) + per-row min/max.
//   K2 k_dist : block i: load featG -> LDS, D2 row i -> D16 (half bits), row-min
//               key via DPP -> rowKeyG.  (No redundant feat recompute.)
//   K3 k_mst  : ONE block, 1024 threads.
//               wave 0: deterministic Boruvka round-1 replay from rowKeyG
//               waves 1-14: INF-init contracted matrix Mb (concurrent)
//               wave 15: min/max reduce                       [syncthreads]
//               all: fold D16 (global, L2/L3) into Mb[ca][cb] via LDS atomicMin
//               wave 0 alone: Boruvka rounds 2+ on LDS (no block barriers)
//               all: structure-element layer (verified 16-partial form).
//
// ws layout:
//   featG [6656] f32 @ 0      (stride 26)
//   fmnG  [256]  f32 @ 26624
//   fmxG  [256]  f32 @ 27648
//   rowKeyG[256] u32 @ 28672
//   D16  [65536] u16 @ 65536

#define WS_FEAT 0
#define WS_FMN  26624
#define WS_FMX  27648
#define WS_RK   28672
#define WS_D16  65536

#define INF32 0xFFFFFFFFu
#define SA 132   // u32 stride, buffer A (cap 128 rows)
#define SB 68    // u32 stride, buffer B (cap 64 rows)
#define OFF_B (128 * SA)

// ---------------- K1: mean + feat row + row min/max (verified R2) ----------------
__global__ void __launch_bounds__(256) k_feat(const float* __restrict__ x,
                                              float* __restrict__ featG,
                                              float* __restrict__ fmnG,
                                              float* __restrict__ fmxG) {
    __shared__ float sums[25];
    __shared__ float mrow[25];
    __shared__ float S12[2];
    __shared__ unsigned int bmn, bmx;
    const int n = blockIdx.x;
    const int tid = threadIdx.x;
    if (tid < 25) sums[tid] = 0.0f;
    if (tid == 0) { bmn = 0x7F800000u; bmx = 0u; }
    __syncthreads();
    if (tid < 200) {
        const float* base = x + (long)n * 19200 + 4 * tid;
        float a0 = 0.f, a1 = 0.f, a2 = 0.f, a3 = 0.f;
        #pragma unroll
        for (int i = 0; i < 24; ++i) {
            float4 v = *reinterpret_cast<const float4*>(base + 800 * i);
            a0 += v.x; a1 += v.y; a2 += v.z; a3 += v.w;
        }
        const int v0 = (4 * tid) % 25;
        atomicAdd(&sums[v0], a0);
        atomicAdd(&sums[(v0 + 1) % 25], a1);
        atomicAdd(&sums[(v0 + 2) % 25], a2);
        atomicAdd(&sums[(v0 + 3) % 25], a3);
    }
    __syncthreads();
    if (tid < 25) mrow[tid] = sums[tid] * (1.0f / 768.0f);
    __syncthreads();
    if (tid == 0) {
        float S1 = 0.f, S2 = 0.f;
        #pragma unroll
        for (int v = 0; v < 25; ++v) { S1 += mrow[v]; S2 += mrow[v] * mrow[v]; }
        S12[0] = S1; S12[1] = S2;
    }
    __syncthreads();
    if (tid < 25) {
        const float r = mrow[tid];
        float q = S12[1] - 2.f * r * S12[0] + 25.f * r * r;
        q = fmaxf(q, 0.f);
        const float f = sqrtf(q);
        featG[n * 26 + tid] = f;
        atomicMin(&bmn, __float_as_uint(f));
        atomicMax(&bmx, __float_as_uint(f));
    }
    __syncthreads();
    if (tid == 0) { fmnG[n] = __uint_as_float(bmn); fmxG[n] = __uint_as_float(bmx); }
}

// wave64 min-reduce step via DPP: result in lane 63
template <int CTRL>
__device__ __forceinline__ unsigned int dpp_min_step(unsigned int v) {
    unsigned int t = (unsigned int)__builtin_amdgcn_update_dpp(
        (int)0xFFFFFFFF, (int)v, CTRL, 0xF, 0xF, false);
    return (t < v) ? t : v;
}

// ---------------- K2: D2 row + row-min key ----------------
__global__ void __launch_bounds__(256) k_dist(const float* __restrict__ featG,
                                              unsigned short* __restrict__ D16,
                                              unsigned int* __restrict__ rowKeyG) {
    __shared__ float featS[6656];          // stride 26 (2-way bank alias: free)
    __shared__ unsigned int wred[4];
    const int i = blockIdx.x;
    const int t = threadIdx.x;
    #pragma unroll
    for (int it = 0; it < 7; ++it) {
        const int o = it * 256 + t;
        if (o < 1664) reinterpret_cast<float4*>(featS)[o] =
            reinterpret_cast<const float4*>(featG)[o];
    }
    __syncthreads();
    float fi[25];
    #pragma unroll
    for (int v = 0; v < 25; ++v) fi[v] = featS[i * 26 + v];   // broadcast reads
    float s = 0.f;
    #pragma unroll
    for (int v = 0; v < 25; ++v) {
        const float d = fi[v] - featS[t * 26 + v];
        s += d * d;
    }
    const unsigned int w16 = (unsigned int)__half_as_ushort(__float2half(s));
    D16[i * 256 + t] = (unsigned short)w16;
    const unsigned int lo = (t < i) ? t : i, hi = (t < i) ? i : t;
    unsigned int key = (t == i) ? INF32 : ((w16 << 16) | (lo << 8) | hi);
    key = dpp_min_step<0x111>(key);
    key = dpp_min_step<0x112>(key);
    key = dpp_min_step<0x114>(key);
    key = dpp_min_step<0x118>(key);
    key = dpp_min_step<0x142>(key);
    key = dpp_min_step<0x143>(key);
    if ((t & 63) == 63) wred[t >> 6] = key;
    __syncthreads();
    if (t == 0) {
        const unsigned int b0 = wred[0] < wred[1] ? wred[0] : wred[1];
        const unsigned int b1 = wred[2] < wred[3] ? wred[2] : wred[3];
        rowKeyG[i] = b0 < b1 ? b0 : b1;
    }
}

// ---------------- wave0 Boruvka phase (verified R0 lineage; returns nc) --------
template <bool RECORD>
__device__ __forceinline__ unsigned int wave0_phase(int n, int lane,
        unsigned int* rowKeyS, unsigned char* parentS, unsigned char* newidS,
        unsigned char* cmapS, float* deaths, unsigned int* ncS, unsigned int* dcS) {
    unsigned int par[4];
    #pragma unroll
    for (int s = 0; s < 4; ++s) {         // hook
        const int i = lane + 64 * s;
        if (i < n) {
            const unsigned int rk = rowKeyS[i];
            const unsigned int u = (rk >> 8) & 0xFFu, v = rk & 0xFFu;
            unsigned int p = (u == (unsigned int)i) ? v : u;
            if (rk == INF32) p = (unsigned int)i;
            par[s] = p;
            parentS[i] = (unsigned char)p;
        }
    }
    #pragma unroll
    for (int s = 0; s < 4; ++s) {         // break mutual 2-cycles
        const int i = lane + 64 * s;
        if (i < n) {
            const unsigned int p = par[s];
            if (p != (unsigned int)i) {
                if (parentS[p] == (unsigned char)i && (unsigned int)i < p) {
                    parentS[i] = (unsigned char)i;   // winner stays root
                } else if (RECORD) {
                    const unsigned int d = atomicAdd(dcS, 1u);
                    const unsigned int rk = rowKeyS[i];
                    deaths[d] = sqrtf(__half2float(__ushort_as_half(
                        (unsigned short)(rk >> 16))));
                }
            }
        }
    }
    for (;;) {                            // async pointer jump
        bool ch = false;
        #pragma unroll
        for (int s = 0; s < 4; ++s) {
            const int i = lane + 64 * s;
            if (i < n) {
                const unsigned char p0 = parentS[i];
                const unsigned char np = parentS[p0];
                if (np != p0) { ch = true; parentS[i] = np; }
            }
        }
        if (__ballot(ch) == 0ull) break;
    }
    bool isr[4];
    #pragma unroll
    for (int s = 0; s < 4; ++s) {
        const int i = lane + 64 * s;
        isr[s] = (i < n) && (parentS[i] == (unsigned char)i);
    }
    unsigned int base = 0;
    const unsigned long long below = (1ull << lane) - 1ull;
    #pragma unroll
    for (int s = 0; s < 4; ++s) {
        const unsigned long long mask = __ballot(isr[s]);   // uniform execution
        if (isr[s]) {
            const int i = lane + 64 * s;
            newidS[i] = (unsigned char)(base + __popcll(mask & below));
        }
        base += (unsigned int)__popcll(mask);
    }
    if (lane == 0) *ncS = base;
    #pragma unroll
    for (int s = 0; s < 4; ++s) {
        const int i = lane + 64 * s;
        if (i < n) cmapS[i] = newidS[parentS[i]];
    }
    return base;            // uniform across lanes
}

// ---------------- K3: replay + fold + rounds 2+ + structure ----------------
__global__ void __launch_bounds__(1024) k_mst(const unsigned short* __restrict__ D16g,
                                              const unsigned int* __restrict__ rowKeyG,
                                              const float* __restrict__ fmnG,
                                              const float* __restrict__ fmxG,
                                              const float* __restrict__ centres,
                                              const float* __restrict__ sharp,
                                              float* __restrict__ out) {
    __shared__ unsigned int Mb[128 * SA + 64 * SB];   // 84.5 KB ping-pong
    __shared__ unsigned int rowKeyS[256];
    __shared__ unsigned char parentS[256], newidS[256], cmapS[256];
    __shared__ unsigned int ncS, dcS;
    __shared__ float deathsS[256];
    __shared__ unsigned int mmS[2];
    __shared__ float outpart[1024];
    const int tid = threadIdx.x;
    const int wv = tid >> 6, lane = tid & 63;

    if (tid < 256) rowKeyS[tid] = rowKeyG[tid];
    if (tid == 0) { dcS = 0; mmS[0] = 0x7F800000u; mmS[1] = 0u; }
    __syncthreads();

    if (wv == 0) {
        // round-1 replay (deterministic): deaths + cmap + nc
        wave0_phase<true>(256, lane, rowKeyS, parentS, newidS, cmapS,
                          deathsS, &ncS, &dcS);
    } else if (wv == 15) {
        // feat min/max reduce
        #pragma unroll
        for (int q = 0; q < 4; ++q) {
            const int j = (tid - 960) * 4 + q;
            atomicMin(&mmS[0], __float_as_uint(fmnG[j]));
            atomicMax(&mmS[1], __float_as_uint(fmxG[j]));
        }
    } else {
        // INF-init full buffer-A region (fixed 128*SA, no dependency on nc)
        for (int w = tid - 64; w < 128 * SA; w += 896) Mb[w] = INF32;
    }
    __syncthreads();

    // fold round-1: D16 (global) -> Mb[ca][cb] via LDS atomicMin
    {
        const unsigned int* D32 = reinterpret_cast<const unsigned int*>(D16g);
        for (int u = tid; u < 32768; u += 1024) {
            const unsigned int w = D32[u];
            const int r = u >> 7;
            const int c = (u & 127) << 1;
            const unsigned int ca = cmapS[r];
            const unsigned int e0 = w & 0xFFFFu;
            const unsigned int e1 = w >> 16;
            const unsigned int cb0 = cmapS[c];
            const unsigned int cb1 = cmapS[c + 1];
            if (ca != cb0) {
                const unsigned int lo = ca < cb0 ? ca : cb0;
                const unsigned int hi = ca < cb0 ? cb0 : ca;
                atomicMin(&Mb[ca * SA + cb0], (e0 << 16) | (lo << 8) | hi);
            }
            if (ca != cb1) {
                const unsigned int lo = ca < cb1 ? ca : cb1;
                const unsigned int hi = ca < cb1 ? cb1 : ca;
                atomicMin(&Mb[ca * SA + cb1], (e1 << 16) | (lo << 8) | hi);
            }
        }
    }
    __syncthreads();

    // rounds 2+ : wave 0 only, no block barriers (n <= 128)
    if (wv == 0) {
        int n = (int)ncS;
        int srcOff = 0, srcStr = SA, dstOff = OFF_B, dstStr = SB;
        for (int round = 0; round < 12 && n > 1; ++round) {
            for (int a = lane; a < n; a += 64) {       // row-min scan (lane owns row)
                const unsigned int* row = &Mb[srcOff + a * srcStr];
                unsigned int best = INF32;
                for (int b2 = 0; b2 < n; ++b2) {
                    const unsigned int v = row[b2];
                    best = v < best ? v : best;
                }
                rowKeyS[a] = best;
            }
            __builtin_amdgcn_wave_barrier();
            const unsigned int nc = wave0_phase<true>(n, lane, rowKeyS, parentS,
                                                      newidS, cmapS, deathsS,
                                                      &ncS, &dcS);
            __builtin_amdgcn_wave_barrier();
            if (nc > 1) {                              // contract src -> dst
                for (int w = lane; w < (int)nc * dstStr; w += 64)
                    Mb[dstOff + w] = INF32;
                __builtin_amdgcn_wave_barrier();
                for (int a = lane; a < n; a += 64) {
                    const unsigned int ca = cmapS[a];
                    const unsigned int* row = &Mb[srcOff + a * srcStr];
                    for (int b2 = 0; b2 < n; ++b2) {
                        const unsigned int cb = cmapS[b2];
                        const unsigned int v = row[b2];
                        if (ca != cb && v != INF32) {
                            const unsigned int lo = ca < cb ? ca : cb;
                            const unsigned int hi = ca < cb ? cb : ca;
                            atomicMin(&Mb[dstOff + ca * dstStr + cb],
                                      (v & 0xFFFF0000u) | (lo << 8) | hi);
                        }
                    }
                }
                __builtin_amdgcn_wave_barrier();
            }
            const int t1 = srcOff; srcOff = dstOff; dstOff = t1;
            const int t2 = srcStr; srcStr = dstStr; dstStr = t2;
            n = (int)nc;
        }
    }
    __syncthreads();

    // structure-element layer (verified 16-partial form)
    const float mn = __uint_as_float(mmS[0]);
    const float mx = __uint_as_float(mmS[1]);
    const float inv = 1.0f / (mx - mn);
    const int k = tid & 63;
    const int part = tid >> 6;
    const float c0 = centres[2 * k], c1 = centres[2 * k + 1];
    const float s0 = sharp[2 * k],   s1 = sharp[2 * k + 1];
    const float t0 = c0 * c0 * s0 * s0;
    const float s1sq = s1 * s1;
    float acc = 0.f;
    for (int idx = part; idx < 255; idx += 16) {
        const float d = deathsS[idx] * inv - c1;
        acc += __expf(-(t0 + d * d * s1sq));
    }
    outpart[tid] = acc;
    __syncthreads();
    if (tid < 64) {
        float s = 0.f;
        #pragma unroll
        for (int pp = 0; pp < 16; ++pp) s += outpart[tid + 64 * pp];
        out[tid] = s;
    }
}

extern "C" void kernel_launch(void* const* d_in, const int* in_sizes, int n_in,
                              void* d_out, int out_size, void* d_ws, size_t ws_size,
                              hipStream_t stream) {
    const float* x       = (const float*)d_in[0];
    const float* centres = (const float*)d_in[1];
    const float* sharp   = (const float*)d_in[2];
    float* out = (float*)d_out;
    char* ws = (char*)d_ws;
    float*          featG = (float*)(ws + WS_FEAT);
    float*          fmnG  = (float*)(ws + WS_FMN);
    float*          fmxG  = (float*)(ws + WS_FMX);
    unsigned int*   rk    = (unsigned int*)(ws + WS_RK);
    unsigned short* D16   = (unsigned short*)(ws + WS_D16);

    k_feat<<<256, 256, 0, stream>>>(x, featG, fmnG, fmxG);
    k_dist<<<256, 256, 0, stream>>>(featG, D16, rk);
    k_mst<<<1, 1024, 0, stream>>>(D16, rk, fmnG, fmxG, centres, sharp, out);
}